// Round 1
// baseline (1289.063 us; speedup 1.0000x reference)
//
#include <hip/hip_runtime.h>

typedef __attribute__((ext_vector_type(8))) short bf16x8;
typedef __attribute__((ext_vector_type(4))) float f32x4;

__device__ __forceinline__ float bf2f(ushort u) {
  union { unsigned int i; float f; } v; v.i = ((unsigned int)u) << 16; return v.f;
}
__device__ __forceinline__ ushort f2bf(float f) {
  union { float f; unsigned int i; } v; v.f = f;
  unsigned int x = v.i;
  unsigned int r = (x + 0x7fffu + ((x >> 16) & 1u)) >> 16;
  return (ushort)r;
}

// ---------------------------------------------------------------- utilities
__global__ void zero_f32(float* p, int n) {
  int i = blockIdx.x * 256 + threadIdx.x;
  if (i < n) p[i] = 0.f;
}

// Pack W[co][ci][ky][kx] (fp32) -> Wp[tap][cic][cf][lane][8] (bf16)
// A-frag layout for mfma_f32_16x16x32_bf16: lane l holds A[row=l&15][k=(l>>4)*8+j]
__global__ void pack_w(const float* __restrict__ W, ushort* __restrict__ Wp, int Cin) {
  int ncic = Cin >> 5;
  int total = 9 * ncic * 8 * 64 * 8;
  for (int idx = blockIdx.x * 256 + threadIdx.x; idx < total; idx += gridDim.x * 256) {
    int j = idx & 7;
    int l = (idx >> 3) & 63;
    int cf = (idx >> 9) & 7;
    int rest = idx >> 12;          // tap*ncic + cic
    int cic = rest % ncic;
    int tap = rest / ncic;
    int co = cf * 16 + (l & 15);
    int ci = cic * 32 + ((l >> 4) * 8) + j;
    int ky = tap / 3, kx = tap % 3;
    Wp[idx] = f2bf(W[((co * Cin + ci) * 3 + ky) * 3 + kx]);
  }
}

// ---------------------------------------------------------------- conv core
// MODE 0: src fp32, plain            (conv1)
// MODE 1: src bf16, relu(a*x+b)      (conv2, coef = BN1 a/b)
// MODE 2: src bf16, plain            (conv3, dwt input)
// Output: raw conv+bias as bf16, plus per-channel sum/sumsq (32 replicas).
template<int MODE>
__global__ __launch_bounds__(256)
void conv_mfma(const void* __restrict__ src, const ushort* __restrict__ Wp,
               const float* __restrict__ bias, const float* __restrict__ coef,
               ushort* __restrict__ out, float* __restrict__ sSum, float* __restrict__ sSsq,
               int Cin, int H, int W)
{
  const int ncic = Cin >> 5;
  const int x0 = blockIdx.x << 6;
  const int y  = blockIdx.y;
  const int n  = blockIdx.z;
  const int tid = threadIdx.x;
  const int wv  = tid >> 6;
  const int l   = tid & 63;
  const int l15 = l & 15;
  const int l4  = l >> 4;

  __shared__ ushort lds[3 * 66 * 40];   // [row][xt][ci], ci padded 32->40 (bank decorrelation)

  f32x4 acc[2][4];
#pragma unroll
  for (int f = 0; f < 2; ++f)
#pragma unroll
    for (int xf = 0; xf < 4; ++xf) acc[f][xf] = (f32x4){0.f, 0.f, 0.f, 0.f};

  const long plane = (long)H * W;

  for (int cic = 0; cic < ncic; ++cic) {
    __syncthreads();
    // stage input patch: rows y-1..y+1, cols x0-1..x0+64, 32 channels
    for (int i = tid; i < 3 * 32 * 66; i += 256) {
      int xt  = i % 66;
      int rc  = i / 66;
      int ci  = rc & 31;
      int row = rc >> 5;
      int ry = y + row - 1;
      int gx = x0 + xt - 1;
      float v = 0.f;
      if ((unsigned)ry < (unsigned)H && (unsigned)gx < (unsigned)W) {
        int c = (cic << 5) + ci;
        long off = ((long)(n * Cin + c)) * plane + (long)ry * W + gx;
        if (MODE == 0) {
          v = ((const float*)src)[off];
        } else if (MODE == 1) {
          float xv = bf2f(((const ushort*)src)[off]);
          v = fmaxf(coef[c] * xv + coef[128 + c], 0.f);
        } else {
          v = bf2f(((const ushort*)src)[off]);
        }
      }
      lds[(row * 66 + xt) * 40 + ci] = f2bf(v);
    }
    __syncthreads();

#pragma unroll
    for (int tap = 0; tap < 9; ++tap) {
      const int ky = tap / 3, kx = tap % 3;
      bf16x8 afr[2];
#pragma unroll
      for (int f = 0; f < 2; ++f) {
        int cf = wv * 2 + f;
        const ushort* p = Wp + ((((size_t)(tap * ncic + cic) * 8 + cf) * 64 + l) * 8);
        afr[f] = *(const bf16x8*)p;
      }
      bf16x8 bfr[4];
#pragma unroll
      for (int xf = 0; xf < 4; ++xf) {
        const ushort* p = &lds[(ky * 66 + (xf * 16 + l15 + kx)) * 40 + l4 * 8];
        bfr[xf] = *(const bf16x8*)p;
      }
#pragma unroll
      for (int f = 0; f < 2; ++f)
#pragma unroll
        for (int xf = 0; xf < 4; ++xf)
          acc[f][xf] = __builtin_amdgcn_mfma_f32_16x16x32_bf16(afr[f], bfr[xf], acc[f][xf], 0, 0, 0);
    }
  }

  // epilogue: bias, raw bf16 store, per-channel stats
  const int rep = (int)((blockIdx.z * gridDim.y + blockIdx.y) * gridDim.x + blockIdx.x) & 31;
#pragma unroll
  for (int f = 0; f < 2; ++f) {
#pragma unroll
    for (int j = 0; j < 4; ++j) {
      int co = wv * 32 + f * 16 + l4 * 4 + j;
      float bv = bias[co];
      float sm = 0.f, sq = 0.f;
#pragma unroll
      for (int xf = 0; xf < 4; ++xf) {
        float v = acc[f][xf][j] + bv;
        int x = x0 + xf * 16 + l15;
        out[((size_t)(n * 128 + co)) * plane + (size_t)y * W + x] = f2bf(v);
        sm += v; sq += v * v;
      }
#pragma unroll
      for (int o = 1; o < 16; o <<= 1) {
        sm += __shfl_xor(sm, o);
        sq += __shfl_xor(sq, o);
      }
      if (l15 == 0) {
        atomicAdd(&sSum[rep * 128 + co], sm);
        atomicAdd(&sSsq[rep * 128 + co], sq);
      }
    }
  }
}

// ---------------------------------------------------------------- BN finalize
__global__ void bn_finalize(const float* __restrict__ sSum, const float* __restrict__ sSsq,
                            const float* __restrict__ g, const float* __restrict__ be,
                            float* __restrict__ coef, float invN)
{
  int c = threadIdx.x;  // 128
  float S = 0.f, Q = 0.f;
  for (int r = 0; r < 32; ++r) { S += sSum[r * 128 + c]; Q += sSsq[r * 128 + c]; }
  float m = S * invN;
  float v = Q * invN - m * m;
  float a = g[c] / sqrtf(v + 1e-5f);
  coef[c] = a;
  coef[128 + c] = be[c] - m * a;
}

// ---------------------------------------------------------------- skip out + DWT
__global__ __launch_bounds__(256)
void skip_dwt(const ushort* __restrict__ skipRaw, const float* __restrict__ coef,
              float* __restrict__ outSkip, ushort* __restrict__ dwt)
{
  int n = blockIdx.z, c = blockIdx.y;
  int t = threadIdx.x;
  int i = (blockIdx.x << 1) + (t >> 7);   // 0..127
  int j = t & 127;                        // 0..127
  float a = coef[c], b = coef[128 + c];
  size_t pbase = ((size_t)(n * 128 + c)) << 16;
  int r0 = ((i * 2) << 8) + j * 2;
  const ushort* sp = skipRaw + pbase;
  ushort2 u0 = *(const ushort2*)(sp + r0);
  ushort2 u1 = *(const ushort2*)(sp + r0 + 256);
  float p00 = fmaxf(a * bf2f(u0.x) + b, 0.f);
  float p01 = fmaxf(a * bf2f(u0.y) + b, 0.f);
  float p10 = fmaxf(a * bf2f(u1.x) + b, 0.f);
  float p11 = fmaxf(a * bf2f(u1.y) + b, 0.f);
  float* op = outSkip + pbase;
  float2 w0; w0.x = p00; w0.y = p01;
  float2 w1; w1.x = p10; w1.y = p11;
  *(float2*)(op + r0) = w0;
  *(float2*)(op + r0 + 256) = w1;
  float cA = (p00 + p01 + p10 + p11) * 0.5f;
  float cH = (p00 + p01 - p10 - p11) * 0.5f;
  float cV = (p00 - p01 + p10 - p11) * 0.5f;
  float cD = (p00 - p01 - p10 + p11) * 0.5f;
  size_t db = (((size_t)(n * 512 + c)) << 14) + (i << 7) + j;
  dwt[db]              = f2bf(cA);
  dwt[db + (128 << 14)] = f2bf(cH);
  dwt[db + (256 << 14)] = f2bf(cV);
  dwt[db + (384 << 14)] = f2bf(cD);
}

// ---------------------------------------------------------------- final BN3 out
__global__ void bn3_out(const ushort* __restrict__ raw, const float* __restrict__ coef,
                        float* __restrict__ out)
{
  size_t idx = ((size_t)blockIdx.x * 256 + threadIdx.x) * 2;
  int c = (int)((idx >> 14) & 127);
  float a = coef[c], b = coef[128 + c];
  ushort2 u = *(const ushort2*)(raw + idx);
  out[idx]     = fmaxf(a * bf2f(u.x) + b, 0.f);
  out[idx + 1] = fmaxf(a * bf2f(u.y) + b, 0.f);
}

// ---------------------------------------------------------------- launch
extern "C" void kernel_launch(void* const* d_in, const int* in_sizes, int n_in,
                              void* d_out, int out_size, void* d_ws, size_t ws_size,
                              hipStream_t stream)
{
  const float* input = (const float*)d_in[0];
  const float* W1  = (const float*)d_in[1];
  const float* b1  = (const float*)d_in[2];
  const float* g1  = (const float*)d_in[3];
  const float* be1 = (const float*)d_in[4];
  const float* W2  = (const float*)d_in[5];
  const float* b2  = (const float*)d_in[6];
  const float* g2  = (const float*)d_in[7];
  const float* be2 = (const float*)d_in[8];
  const float* W3  = (const float*)d_in[9];
  const float* b3  = (const float*)d_in[10];
  const float* g3  = (const float*)d_in[11];
  const float* be3 = (const float*)d_in[12];

  char* ws = (char*)d_ws;
  ushort* h_raw    = (ushort*)(ws + 0);            // 134217728 B
  ushort* skip_raw = (ushort*)(ws + 134217728);    // 134217728 B
  ushort* dwt      = (ushort*)(ws + 268435456);    // 134217728 B
  ushort* raw3     = (ushort*)(ws + 402653184);    // 33554432 B
  float*  stats    = (float*)(ws + 436207616);     // 24576 floats
  float*  s1 = stats,          *q1 = stats + 4096;
  float*  s2 = stats + 8192,   *q2 = stats + 12288;
  float*  s3 = stats + 16384,  *q3 = stats + 20480;
  float*  coef = (float*)(ws + 436305920);         // 768 floats
  float*  c1 = coef, *c2 = coef + 256, *c3 = coef + 512;
  ushort* Wp1 = (ushort*)(ws + 436308992);         // 147456 B
  ushort* Wp2 = (ushort*)(ws + 436456448);         // 294912 B
  ushort* Wp3 = (ushort*)(ws + 436751360);         // 1179648 B

  zero_f32<<<96, 256, 0, stream>>>(stats, 24576);
  pack_w<<<288, 256, 0, stream>>>(W1, Wp1, 64);
  pack_w<<<576, 256, 0, stream>>>(W2, Wp2, 128);
  pack_w<<<2304, 256, 0, stream>>>(W3, Wp3, 512);

  // conv1: (8,64,256,256) -> h_raw (8,128,256,256)
  conv_mfma<0><<<dim3(4, 256, 8), 256, 0, stream>>>(input, Wp1, b1, nullptr,
                                                    h_raw, s1, q1, 64, 256, 256);
  bn_finalize<<<1, 128, 0, stream>>>(s1, q1, g1, be1, c1, 1.f / 524288.f);

  // conv2: bn_relu(h) -> skip_raw
  conv_mfma<1><<<dim3(4, 256, 8), 256, 0, stream>>>(h_raw, Wp2, b2, c1,
                                                    skip_raw, s2, q2, 128, 256, 256);
  bn_finalize<<<1, 128, 0, stream>>>(s2, q2, g2, be2, c2, 1.f / 524288.f);

  // skip_con (fp32 out) + DWT (bf16)
  skip_dwt<<<dim3(64, 128, 8), 256, 0, stream>>>(skip_raw, c2, (float*)d_out, dwt);

  // conv3: dwt (8,512,128,128) -> raw3 (8,128,128,128)
  conv_mfma<2><<<dim3(2, 128, 8), 256, 0, stream>>>(dwt, Wp3, b3, nullptr,
                                                    raw3, s3, q3, 512, 128, 128);
  bn_finalize<<<1, 128, 0, stream>>>(s3, q3, g3, be3, c3, 1.f / 131072.f);

  bn3_out<<<32768, 256, 0, stream>>>(raw3, c3, (float*)d_out + 67108864);
}

// Round 2
// 726.601 us; speedup vs baseline: 1.7741x; 1.7741x over previous
//
#include <hip/hip_runtime.h>

typedef __attribute__((ext_vector_type(8))) short bf16x8;
typedef __attribute__((ext_vector_type(4))) short bf16x4;
typedef __attribute__((ext_vector_type(4))) float f32x4;

__device__ __forceinline__ float bf2f(ushort u) {
  union { unsigned int i; float f; } v; v.i = ((unsigned int)u) << 16; return v.f;
}
__device__ __forceinline__ ushort f2bf(float f) {
  union { float f; unsigned int i; } v; v.f = f;
  unsigned int x = v.i;
  unsigned int r = (x + 0x7fffu + ((x >> 16) & 1u)) >> 16;
  return (ushort)r;
}

// ---------------------------------------------------------------- utilities
__global__ void zero_f32(float* p, int n) {
  int i = blockIdx.x * 256 + threadIdx.x;
  if (i < n) p[i] = 0.f;
}

// Pack W[co][ci][ky][kx] (fp32) -> Wp[tap][cic][cf][lane][8] (bf16)
__global__ void pack_w(const float* __restrict__ W, ushort* __restrict__ Wp, int Cin) {
  int ncic = Cin >> 5;
  int total = 9 * ncic * 8 * 64 * 8;
  for (int idx = blockIdx.x * 256 + threadIdx.x; idx < total; idx += gridDim.x * 256) {
    int j = idx & 7;
    int l = (idx >> 3) & 63;
    int cf = (idx >> 9) & 7;
    int rest = idx >> 12;
    int cic = rest % ncic;
    int tap = rest / ncic;
    int co = cf * 16 + (l & 15);
    int ci = cic * 32 + ((l >> 4) * 8) + j;
    int ky = tap / 3, kx = tap % 3;
    Wp[idx] = f2bf(W[((co * Cin + ci) * 3 + ky) * 3 + kx]);
  }
}

// NCHW fp32 [8][64][65536] -> NHWC bf16 [8][65536][64]
__global__ __launch_bounds__(256)
void nchw2nhwc(const float* __restrict__ in, ushort* __restrict__ out) {
  const int n  = blockIdx.y;
  const int p0 = blockIdx.x << 6;
  const int tid = threadIdx.x;
  __shared__ ushort t[64 * 72];   // [pix][c], c padded 64->72
  {
    int c  = tid >> 2;
    int pq = (tid & 3) << 4;
    const float* ip = in + (((size_t)(n * 64 + c)) << 16) + p0 + pq;
#pragma unroll
    for (int k = 0; k < 4; ++k) {
      float4 f = *(const float4*)(ip + k * 4);
      int p = pq + k * 4;
      t[(p + 0) * 72 + c] = f2bf(f.x);
      t[(p + 1) * 72 + c] = f2bf(f.y);
      t[(p + 2) * 72 + c] = f2bf(f.z);
      t[(p + 3) * 72 + c] = f2bf(f.w);
    }
  }
  __syncthreads();
#pragma unroll
  for (int k = 0; k < 2; ++k) {
    int id = k * 256 + tid;
    int cj = id & 7, p = id >> 3;
    bf16x8 v = *(const bf16x8*)&t[p * 72 + cj * 8];
    *(bf16x8*)(out + ((((size_t)n << 16) + p0 + p) << 6) + cj * 8) = v;
  }
}

__device__ __forceinline__ bf16x8 bnrelu8(bf16x8 v, const float* __restrict__ coef, int c0) {
  float4 a0 = *(const float4*)(coef + c0);
  float4 a1 = *(const float4*)(coef + c0 + 4);
  float4 b0 = *(const float4*)(coef + 128 + c0);
  float4 b1 = *(const float4*)(coef + 128 + c0 + 4);
  bf16x8 r;
  r[0] = (short)f2bf(fmaxf(a0.x * bf2f((ushort)v[0]) + b0.x, 0.f));
  r[1] = (short)f2bf(fmaxf(a0.y * bf2f((ushort)v[1]) + b0.y, 0.f));
  r[2] = (short)f2bf(fmaxf(a0.z * bf2f((ushort)v[2]) + b0.z, 0.f));
  r[3] = (short)f2bf(fmaxf(a0.w * bf2f((ushort)v[3]) + b0.w, 0.f));
  r[4] = (short)f2bf(fmaxf(a1.x * bf2f((ushort)v[4]) + b1.x, 0.f));
  r[5] = (short)f2bf(fmaxf(a1.y * bf2f((ushort)v[5]) + b1.y, 0.f));
  r[6] = (short)f2bf(fmaxf(a1.z * bf2f((ushort)v[6]) + b1.z, 0.f));
  r[7] = (short)f2bf(fmaxf(a1.w * bf2f((ushort)v[7]) + b1.w, 0.f));
  return r;
}

// ---------------------------------------------------------------- conv core (NHWC)
// src NHWC bf16 [n][H*W][Cin]; out NHWC bf16 [n][H*W][128].
// MODE 0: plain; MODE 1: relu(a*x+b) applied during staging (coef).
// Block: 64 x * 2 y * 128 co.
template<int MODE>
__global__ __launch_bounds__(256)
void conv_mfma(const ushort* __restrict__ src, const ushort* __restrict__ Wp,
               const float* __restrict__ bias, const float* __restrict__ coef,
               ushort* __restrict__ out, float* __restrict__ sSum, float* __restrict__ sSsq,
               int Cin, int H, int W)
{
  const int ncic = Cin >> 5;
  const int x0 = blockIdx.x << 6;
  const int y0 = blockIdx.y << 1;
  const int n  = blockIdx.z;
  const int tid = threadIdx.x;
  const int wv = tid >> 6, l = tid & 63, l15 = l & 15, l4 = l >> 4;

  __shared__ __align__(16) char smem[17408];
  ushort* lds = (ushort*)smem;   // staging: [row4][cj4][xt66][8] = 16896 B
  ushort* eps = (ushort*)smem;   // epilogue: [x64][co 136] = 17408 B

  f32x4 acc[2][2][4];
#pragma unroll
  for (int yr = 0; yr < 2; ++yr)
#pragma unroll
    for (int f = 0; f < 2; ++f)
#pragma unroll
      for (int xf = 0; xf < 4; ++xf) acc[yr][f][xf] = (f32x4){0.f, 0.f, 0.f, 0.f};

  const size_t HW = (size_t)H * W;

  for (int cic = 0; cic < ncic; ++cic) {
    __syncthreads();
    for (int i = tid; i < 1056; i += 256) {
      int cj = i & 3;
      int t = i >> 2;
      int row = t / 66;
      int xt = t - row * 66;
      int ry = y0 + row - 1;
      int gx = x0 + xt - 1;
      bf16x8 v = {};
      if ((unsigned)ry < (unsigned)H && (unsigned)gx < (unsigned)W) {
        const ushort* p = src + ((size_t)n * HW + (size_t)ry * W + gx) * Cin + (cic << 5) + (cj << 3);
        v = *(const bf16x8*)p;
        if (MODE == 1) v = bnrelu8(v, coef, (cic << 5) + (cj << 3));
      }
      *(bf16x8*)&lds[(((row << 2) | cj) * 66 + xt) << 3] = v;
    }
    __syncthreads();

#pragma unroll
    for (int tap = 0; tap < 9; ++tap) {
      const int ky = tap / 3, kx = tap % 3;
      bf16x8 afr[2];
#pragma unroll
      for (int f = 0; f < 2; ++f) {
        const int cf = (wv << 1) | f;
        afr[f] = *(const bf16x8*)(Wp + (((size_t)(tap * ncic + cic) * 8 + cf) * 64 + l) * 8);
      }
      bf16x8 bfr[2][4];
#pragma unroll
      for (int yr = 0; yr < 2; ++yr)
#pragma unroll
        for (int xf = 0; xf < 4; ++xf) {
          int row = yr + ky;
          int xt = (xf << 4) + l15 + kx;
          bfr[yr][xf] = *(const bf16x8*)&lds[(((row << 2) | l4) * 66 + xt) << 3];
        }
#pragma unroll
      for (int f = 0; f < 2; ++f)
#pragma unroll
        for (int yr = 0; yr < 2; ++yr)
#pragma unroll
          for (int xf = 0; xf < 4; ++xf)
            acc[yr][f][xf] = __builtin_amdgcn_mfma_f32_16x16x32_bf16(afr[f], bfr[yr][xf], acc[yr][f][xf], 0, 0, 0);
    }
  }

  // ------------- epilogue: bias, stats, NHWC store via LDS transpose
  float sm[2][4] = {{0.f}}, sq[2][4] = {{0.f}};
  const int cb = (wv << 5) + (l4 << 2);
  for (int yr = 0; yr < 2; ++yr) {
    __syncthreads();
#pragma unroll
    for (int f = 0; f < 2; ++f) {
      const int cf = cb + (f << 4);
      float4 bv = *(const float4*)(bias + cf);
#pragma unroll
      for (int xf = 0; xf < 4; ++xf) {
        float v0 = acc[yr][f][xf][0] + bv.x;
        float v1 = acc[yr][f][xf][1] + bv.y;
        float v2 = acc[yr][f][xf][2] + bv.z;
        float v3 = acc[yr][f][xf][3] + bv.w;
        sm[f][0] += v0; sq[f][0] += v0 * v0;
        sm[f][1] += v1; sq[f][1] += v1 * v1;
        sm[f][2] += v2; sq[f][2] += v2 * v2;
        sm[f][3] += v3; sq[f][3] += v3 * v3;
        bf16x4 u;
        u[0] = (short)f2bf(v0); u[1] = (short)f2bf(v1);
        u[2] = (short)f2bf(v2); u[3] = (short)f2bf(v3);
        *(bf16x4*)&eps[((xf << 4) + l15) * 136 + cf] = u;
      }
    }
    __syncthreads();
    {
      const int xx = tid >> 2, c0 = (tid & 3) << 5;
      ushort* op = out + ((size_t)n * HW + (size_t)(y0 + yr) * W + x0 + xx) * 128 + c0;
#pragma unroll
      for (int k = 0; k < 4; ++k) {
        bf16x8 v = *(const bf16x8*)&eps[xx * 136 + c0 + (k << 3)];
        *(bf16x8*)(op + (k << 3)) = v;
      }
    }
  }

  const int rep = (int)((blockIdx.z * gridDim.y + blockIdx.y) * gridDim.x + blockIdx.x) & 31;
#pragma unroll
  for (int f = 0; f < 2; ++f)
#pragma unroll
    for (int j = 0; j < 4; ++j) {
      float s = sm[f][j], q = sq[f][j];
#pragma unroll
      for (int o = 1; o < 16; o <<= 1) { s += __shfl_xor(s, o); q += __shfl_xor(q, o); }
      if (l15 == 0) {
        int co = cb + (f << 4) + j;
        atomicAdd(&sSum[rep * 128 + co], s);
        atomicAdd(&sSsq[rep * 128 + co], q);
      }
    }
}

// ---------------------------------------------------------------- BN finalize
__global__ void bn_finalize(const float* __restrict__ sSum, const float* __restrict__ sSsq,
                            const float* __restrict__ g, const float* __restrict__ be,
                            float* __restrict__ coef, float invN)
{
  int c = threadIdx.x;  // 128
  float S = 0.f, Q = 0.f;
  for (int r = 0; r < 32; ++r) { S += sSum[r * 128 + c]; Q += sSsq[r * 128 + c]; }
  float m = S * invN;
  float v = Q * invN - m * m;
  float a = g[c] / sqrtf(v + 1e-5f);
  coef[c] = a;
  coef[128 + c] = be[c] - m * a;
}

// ---------------------------------------------------------------- bn_relu + NHWC->NCHW fp32 out
// src NHWC bf16 [n][H*W][128]; dst NCHW fp32. Tile: 32 c x 64 x per block.
__global__ __launch_bounds__(256)
void bn_transpose_out(const ushort* __restrict__ src, const float* __restrict__ coef,
                      float* __restrict__ dst, int H, int W)
{
  const int n  = blockIdx.z >> 2;
  const int cc = blockIdx.z & 3;
  const int x0 = blockIdx.x << 6;
  const int y  = blockIdx.y;
  const int tid = threadIdx.x;
  __shared__ float t[32 * 68];   // [c][x], x padded 64->68
  const size_t HW = (size_t)H * W;
  {
    int p = tid >> 2, cj = tid & 3;
    int c0 = (cc << 5) + (cj << 3);
    bf16x8 v = *(const bf16x8*)(src + ((size_t)n * HW + (size_t)y * W + x0 + p) * 128 + c0);
    float4 a0 = *(const float4*)(coef + c0);
    float4 a1 = *(const float4*)(coef + c0 + 4);
    float4 b0 = *(const float4*)(coef + 128 + c0);
    float4 b1 = *(const float4*)(coef + 128 + c0 + 4);
    int cl = cj << 3;
    t[(cl + 0) * 68 + p] = fmaxf(a0.x * bf2f((ushort)v[0]) + b0.x, 0.f);
    t[(cl + 1) * 68 + p] = fmaxf(a0.y * bf2f((ushort)v[1]) + b0.y, 0.f);
    t[(cl + 2) * 68 + p] = fmaxf(a0.z * bf2f((ushort)v[2]) + b0.z, 0.f);
    t[(cl + 3) * 68 + p] = fmaxf(a0.w * bf2f((ushort)v[3]) + b0.w, 0.f);
    t[(cl + 4) * 68 + p] = fmaxf(a1.x * bf2f((ushort)v[4]) + b1.x, 0.f);
    t[(cl + 5) * 68 + p] = fmaxf(a1.y * bf2f((ushort)v[5]) + b1.y, 0.f);
    t[(cl + 6) * 68 + p] = fmaxf(a1.z * bf2f((ushort)v[6]) + b1.z, 0.f);
    t[(cl + 7) * 68 + p] = fmaxf(a1.w * bf2f((ushort)v[7]) + b1.w, 0.f);
  }
  __syncthreads();
  {
    int c = tid >> 3, x8 = (tid & 7) << 3;
    float4 r0 = *(const float4*)&t[c * 68 + x8];
    float4 r1 = *(const float4*)&t[c * 68 + x8 + 4];
    float* op = dst + ((size_t)(n * 128 + (cc << 5) + c)) * HW + (size_t)y * W + x0 + x8;
    *(float4*)op = r0;
    *(float4*)(op + 4) = r1;
  }
}

// ---------------------------------------------------------------- DWT (NHWC -> NHWC)
// src [8][256*256][128] bf16 raw; dwt [8][128*128][512] bf16 (bn_relu applied via coef).
__global__ __launch_bounds__(256)
void dwt_nhwc(const ushort* __restrict__ src, const float* __restrict__ coef,
              ushort* __restrict__ dwt)
{
  int idx = blockIdx.x * 256 + threadIdx.x;
  int cj = idx & 15;
  int ox = (idx >> 4) & 127;
  int oy = (idx >> 11) & 127;
  int n  = idx >> 18;
  int c0 = cj << 3;
  size_t base = (((size_t)n << 16) + (size_t)(oy * 2) * 256 + ox * 2) * 128 + c0;
  bf16x8 u00 = *(const bf16x8*)(src + base);
  bf16x8 u01 = *(const bf16x8*)(src + base + 128);
  bf16x8 u10 = *(const bf16x8*)(src + base + 256 * 128);
  bf16x8 u11 = *(const bf16x8*)(src + base + 256 * 128 + 128);
  float4 a0 = *(const float4*)(coef + c0);
  float4 a1 = *(const float4*)(coef + c0 + 4);
  float4 b0 = *(const float4*)(coef + 128 + c0);
  float4 b1 = *(const float4*)(coef + 128 + c0 + 4);
  float av[8] = {a0.x, a0.y, a0.z, a0.w, a1.x, a1.y, a1.z, a1.w};
  float bv[8] = {b0.x, b0.y, b0.z, b0.w, b1.x, b1.y, b1.z, b1.w};
  bf16x8 oA, oH, oV, oD;
#pragma unroll
  for (int k = 0; k < 8; ++k) {
    float p00 = fmaxf(av[k] * bf2f((ushort)u00[k]) + bv[k], 0.f);
    float p01 = fmaxf(av[k] * bf2f((ushort)u01[k]) + bv[k], 0.f);
    float p10 = fmaxf(av[k] * bf2f((ushort)u10[k]) + bv[k], 0.f);
    float p11 = fmaxf(av[k] * bf2f((ushort)u11[k]) + bv[k], 0.f);
    oA[k] = (short)f2bf((p00 + p01 + p10 + p11) * 0.5f);
    oH[k] = (short)f2bf((p00 + p01 - p10 - p11) * 0.5f);
    oV[k] = (short)f2bf((p00 - p01 + p10 - p11) * 0.5f);
    oD[k] = (short)f2bf((p00 - p01 - p10 + p11) * 0.5f);
  }
  size_t db = (((size_t)n << 14) + oy * 128 + ox) * 512 + c0;
  *(bf16x8*)(dwt + db)       = oA;
  *(bf16x8*)(dwt + db + 128) = oH;
  *(bf16x8*)(dwt + db + 256) = oV;
  *(bf16x8*)(dwt + db + 384) = oD;
}

// ---------------------------------------------------------------- launch
extern "C" void kernel_launch(void* const* d_in, const int* in_sizes, int n_in,
                              void* d_out, int out_size, void* d_ws, size_t ws_size,
                              hipStream_t stream)
{
  const float* input = (const float*)d_in[0];
  const float* W1  = (const float*)d_in[1];
  const float* b1  = (const float*)d_in[2];
  const float* g1  = (const float*)d_in[3];
  const float* be1 = (const float*)d_in[4];
  const float* W2  = (const float*)d_in[5];
  const float* b2  = (const float*)d_in[6];
  const float* g2  = (const float*)d_in[7];
  const float* be2 = (const float*)d_in[8];
  const float* W3  = (const float*)d_in[9];
  const float* b3  = (const float*)d_in[10];
  const float* g3  = (const float*)d_in[11];
  const float* be3 = (const float*)d_in[12];

  char* ws = (char*)d_ws;
  ushort* h_raw    = (ushort*)(ws + 0);            // NHWC [8][65536][128]
  ushort* skip_raw = (ushort*)(ws + 134217728);    // NHWC [8][65536][128]
  ushort* dwt      = (ushort*)(ws + 268435456);    // NHWC [8][16384][512]
  ushort* in_nhwc  = (ushort*)(ws + 268435456);    // NHWC [8][65536][64] (aliased w/ dwt; dead before dwt written)
  ushort* raw3     = (ushort*)(ws + 402653184);    // NHWC [8][16384][128]
  float*  stats    = (float*)(ws + 436207616);
  float*  s1 = stats,          *q1 = stats + 4096;
  float*  s2 = stats + 8192,   *q2 = stats + 12288;
  float*  s3 = stats + 16384,  *q3 = stats + 20480;
  float*  coef = (float*)(ws + 436305920);
  float*  c1 = coef, *c2 = coef + 256, *c3 = coef + 512;
  ushort* Wp1 = (ushort*)(ws + 436308992);
  ushort* Wp2 = (ushort*)(ws + 436456448);
  ushort* Wp3 = (ushort*)(ws + 436751360);

  zero_f32<<<96, 256, 0, stream>>>(stats, 24576);
  pack_w<<<288, 256, 0, stream>>>(W1, Wp1, 64);
  pack_w<<<576, 256, 0, stream>>>(W2, Wp2, 128);
  pack_w<<<2304, 256, 0, stream>>>(W3, Wp3, 512);
  nchw2nhwc<<<dim3(1024, 8), 256, 0, stream>>>(input, in_nhwc);

  conv_mfma<0><<<dim3(4, 128, 8), 256, 0, stream>>>(in_nhwc, Wp1, b1, nullptr,
                                                    h_raw, s1, q1, 64, 256, 256);
  bn_finalize<<<1, 128, 0, stream>>>(s1, q1, g1, be1, c1, 1.f / 524288.f);

  conv_mfma<1><<<dim3(4, 128, 8), 256, 0, stream>>>(h_raw, Wp2, b2, c1,
                                                    skip_raw, s2, q2, 128, 256, 256);
  bn_finalize<<<1, 128, 0, stream>>>(s2, q2, g2, be2, c2, 1.f / 524288.f);

  bn_transpose_out<<<dim3(4, 256, 32), 256, 0, stream>>>(skip_raw, c2, (float*)d_out, 256, 256);
  dwt_nhwc<<<8192, 256, 0, stream>>>(skip_raw, c2, dwt);

  conv_mfma<0><<<dim3(2, 64, 8), 256, 0, stream>>>(dwt, Wp3, b3, nullptr,
                                                   raw3, s3, q3, 512, 128, 128);
  bn_finalize<<<1, 128, 0, stream>>>(s3, q3, g3, be3, c3, 1.f / 131072.f);

  bn_transpose_out<<<dim3(2, 128, 32), 256, 0, stream>>>(raw3, c3, (float*)d_out + 67108864, 128, 128);
}